// Round 1
// baseline (58.180 us; speedup 1.0000x reference)
//
#include <hip/hip_runtime.h>
#include <math.h>

namespace {

constexpr int B_ = 8, W_ = 64, T_ = 256, D_ = 256;
constexpr int TI_ = 32, WL_ = 16, WP_ = 24, G_ = 64;

// -------- workspace layout (float offsets) --------
constexpr int WS_TFEAT = 0;                         // B*T*D
constexpr int WS_WFEAT = WS_TFEAT + B_ * T_ * D_;   // B*W*D
constexpr int WS_GFEAT = WS_WFEAT + B_ * W_ * D_;   // B*D
constexpr int WS_ST    = WS_GFEAT + B_ * D_;        // B*T
constexpr int WS_SUMT  = WS_ST + B_ * T_;
constexpr int WS_SST   = WS_SUMT + B_ * T_;
constexpr int WS_SW    = WS_SST + B_ * T_;          // B*W
constexpr int WS_SUMW  = WS_SW + B_ * W_;
constexpr int WS_SSW   = WS_SUMW + B_ * W_;
constexpr int WS_SG    = WS_SSW + B_ * W_;          // B
constexpr int WS_SUMG  = WS_SG + B_;
constexpr int WS_SSG   = WS_SUMG + B_;
constexpr int WS_C0    = WS_SSG + B_;
constexpr int WS_C1    = WS_C0 + 1;

__device__ __forceinline__ float wave_sum(float v) {
#pragma unroll
  for (int m = 32; m > 0; m >>= 1) v += __shfl_xor(v, m, 64);
  return v;
}

// X (R rows, stride xstride, in LDS) @ W (K x D, global). Thread owns column d.
template <int R, int K>
__device__ __forceinline__ void row_gemm(const float* __restrict__ Wm,
                                         const float* xl, int xstride, int d,
                                         float* acc) {
#pragma unroll
  for (int r = 0; r < R; ++r) acc[r] = 0.f;
  for (int k = 0; k < K; k += 4) {
    float w0 = Wm[(k + 0) * D_ + d];
    float w1 = Wm[(k + 1) * D_ + d];
    float w2 = Wm[(k + 2) * D_ + d];
    float w3 = Wm[(k + 3) * D_ + d];
#pragma unroll
    for (int r = 0; r < R; ++r) {
      float4 xv = *reinterpret_cast<const float4*>(&xl[r * xstride + k]);
      acc[r] = fmaf(xv.x, w0, acc[r]);
      acc[r] = fmaf(xv.y, w1, acc[r]);
      acc[r] = fmaf(xv.z, w2, acc[r]);
      acc[r] = fmaf(xv.w, w3, acc[r]);
    }
  }
}

// LayerNorm R rows of h (LDS, stride D), write to dst, and emit fusion stats
// (S = sum v*fn_g*aw, sum v, sum v^2) for the actor-LN decomposition.
template <int R>
__device__ __forceinline__ void ln_stats(const float* h,
                                         const float* __restrict__ g,
                                         const float* __restrict__ bt,
                                         const float* __restrict__ fn_g_seg,
                                         const float* __restrict__ aw_seg,
                                         float* __restrict__ dst, int grow0,
                                         float* __restrict__ Sarr,
                                         float* __restrict__ sumarr,
                                         float* __restrict__ ssarr, int tid) {
  const int wv = tid >> 6, lane = tid & 63;
  for (int r = wv; r < R; r += 4) {
    float s = 0.f, ss = 0.f;
    for (int j = lane; j < D_; j += 64) {
      float v = h[r * D_ + j];
      s += v;
      ss = fmaf(v, v, ss);
    }
    s = wave_sum(s);
    ss = wave_sum(ss);
    float mu = s * (1.f / D_);
    float var = ss * (1.f / D_) - mu * mu;
    float inv = rsqrtf(var + 1e-5f);
    float a1 = 0.f, a2 = 0.f, a3 = 0.f;
    for (int j = lane; j < D_; j += 64) {
      float v = (h[r * D_ + j] - mu) * inv * g[j] + bt[j];
      dst[(grow0 + r) * D_ + j] = v;
      a1 = fmaf(v, fn_g_seg[j] * aw_seg[j], a1);
      a2 += v;
      a3 = fmaf(v, v, a3);
    }
    a1 = wave_sum(a1);
    a2 = wave_sum(a2);
    a3 = wave_sum(a3);
    if (lane == 0) {
      Sarr[grow0 + r] = a1;
      sumarr[grow0 + r] = a2;
      ssarr[grow0 + r] = a3;
    }
  }
}

__global__ __launch_bounds__(256) void enc_kernel(
    const float* __restrict__ task_obs, const float* __restrict__ worker_loads,
    const float* __restrict__ worker_profiles,
    const float* __restrict__ global_context, const float* __restrict__ te_w1,
    const float* __restrict__ te_b1, const float* __restrict__ te_w2,
    const float* __restrict__ te_b2, const float* __restrict__ wle_w1,
    const float* __restrict__ wle_b1, const float* __restrict__ wle_w2,
    const float* __restrict__ wle_b2, const float* __restrict__ wpe_w1,
    const float* __restrict__ wpe_b1, const float* __restrict__ wpe_w2,
    const float* __restrict__ wpe_b2, const float* __restrict__ ft_w,
    const float* __restrict__ ft_b, const float* __restrict__ ft_g,
    const float* __restrict__ ft_bt, const float* __restrict__ fw_w,
    const float* __restrict__ fw_b, const float* __restrict__ fw_g,
    const float* __restrict__ fw_bt, const float* __restrict__ g_w1,
    const float* __restrict__ g_b1, const float* __restrict__ g_w2,
    const float* __restrict__ g_b2, const float* __restrict__ fn_g,
    const float* __restrict__ fn_b, const float* __restrict__ actor_w,
    const float* __restrict__ actor_b, float* __restrict__ ws) {
  __shared__ __align__(16) float sm[8 * 512 + 8 * 256 + 8 * 64];
  float* cat = sm;           // 4096 floats
  float* mid = sm + 4096;    // 2048 floats
  float* xs  = sm + 6144;    // 512 floats
  const int tid = threadIdx.x;
  const int d = tid;
  const int blk = blockIdx.x;

  if (blk < 128) {
    // ---------------- worker path: 4 rows/block ----------------
    const int rb = blk * 4;  // row base in [0, 512)
    float* xl = xs;          // 4*16
    float* xp = xs + 64;     // 4*24
    if (tid < 64) xl[tid] = worker_loads[rb * WL_ + tid];
    if (tid < 96) xp[tid] = worker_profiles[rb * WP_ + tid];
    __syncthreads();
    float acc[4];
    row_gemm<4, WL_>(wle_w1, xl, WL_, d, acc);
    {
      float b = wle_b1[d];
#pragma unroll
      for (int r = 0; r < 4; ++r) mid[r * D_ + d] = fmaxf(acc[r] + b, 0.f);
    }
    __syncthreads();
    row_gemm<4, D_>(wle_w2, mid, D_, d, acc);
    {
      float b = wle_b2[d];
#pragma unroll
      for (int r = 0; r < 4; ++r) cat[r * 512 + d] = acc[r] + b;
    }
    __syncthreads();
    row_gemm<4, WP_>(wpe_w1, xp, WP_, d, acc);
    {
      float b = wpe_b1[d];
#pragma unroll
      for (int r = 0; r < 4; ++r) mid[r * D_ + d] = fmaxf(acc[r] + b, 0.f);
    }
    __syncthreads();
    row_gemm<4, D_>(wpe_w2, mid, D_, d, acc);
    {
      float b = wpe_b2[d];
#pragma unroll
      for (int r = 0; r < 4; ++r) cat[r * 512 + 256 + d] = acc[r] + b;
    }
    __syncthreads();
    row_gemm<4, 2 * D_>(fw_w, cat, 512, d, acc);
    {
      float b = fw_b[d];
#pragma unroll
      for (int r = 0; r < 4; ++r) mid[r * D_ + d] = fmaxf(acc[r] + b, 0.f);
    }
    __syncthreads();
    ln_stats<4>(mid, fw_g, fw_bt, fn_g, actor_w, ws + WS_WFEAT, rb, ws + WS_SW,
                ws + WS_SUMW, ws + WS_SSW, tid);
  } else if (blk < 384) {
    // ---------------- task path: 8 rows/block ----------------
    const int rb = (blk - 128) * 8;  // row base in [0, 2048)
    xs[tid] = task_obs[rb * TI_ + tid];  // 8*32 = 256 contiguous floats
    __syncthreads();
    float acc[8];
    row_gemm<8, TI_>(te_w1, xs, TI_, d, acc);
    {
      float b = te_b1[d];
#pragma unroll
      for (int r = 0; r < 8; ++r) mid[r * D_ + d] = fmaxf(acc[r] + b, 0.f);
    }
    __syncthreads();
    row_gemm<8, D_>(te_w2, mid, D_, d, acc);
    {
      float b = te_b2[d];
#pragma unroll
      for (int r = 0; r < 8; ++r) cat[r * D_ + d] = acc[r] + b;
    }
    __syncthreads();
    row_gemm<8, D_>(ft_w, cat, D_, d, acc);
    {
      float b = ft_b[d];
#pragma unroll
      for (int r = 0; r < 8; ++r) mid[r * D_ + d] = fmaxf(acc[r] + b, 0.f);
    }
    __syncthreads();
    ln_stats<8>(mid, ft_g, ft_bt, fn_g + 256, actor_w + 256, ws + WS_TFEAT, rb,
                ws + WS_ST, ws + WS_SUMT, ws + WS_SST, tid);
  } else {
    // ---------------- global path: 8 rows (one block) ----------------
    xs[tid] = global_context[tid];
    xs[tid + 256] = global_context[tid + 256];
    __syncthreads();
    float acc[8];
    row_gemm<8, G_>(g_w1, xs, G_, d, acc);
    {
      float b = g_b1[d];
#pragma unroll
      for (int r = 0; r < 8; ++r) mid[r * D_ + d] = fmaxf(acc[r] + b, 0.f);
    }
    __syncthreads();
    row_gemm<8, D_>(g_w2, mid, D_, d, acc);
    {
      float b = g_b2[d];
#pragma unroll
      for (int r = 0; r < 8; ++r) {
        float v = acc[r] + b;
        ws[WS_GFEAT + r * D_ + d] = v;
        cat[r * D_ + d] = v;
      }
    }
    // C0/C1 partials (independent of cat)
    float c0 = 0.f, c1 = 0.f;
    for (int i = tid; i < 768; i += 256) {
      float aw = actor_w[i];
      c0 = fmaf(fn_b[i], aw, c0);
      c1 = fmaf(fn_g[i], aw, c1);
    }
    mid[tid] = c0;        // mid free: last read was before previous barrier
    mid[512 + tid] = c1;
    __syncthreads();
    const int wv = tid >> 6, lane = tid & 63;
    for (int r = wv; r < 8; r += 4) {
      float a1 = 0.f, a2 = 0.f, a3 = 0.f;
      for (int j = lane; j < D_; j += 64) {
        float v = cat[r * D_ + j];
        a1 = fmaf(v, fn_g[512 + j] * actor_w[512 + j], a1);
        a2 += v;
        a3 = fmaf(v, v, a3);
      }
      a1 = wave_sum(a1);
      a2 = wave_sum(a2);
      a3 = wave_sum(a3);
      if (lane == 0) {
        ws[WS_SG + r] = a1;
        ws[WS_SUMG + r] = a2;
        ws[WS_SSG + r] = a3;
      }
    }
    if (tid == 0) {
      float s0 = 0.f, s1 = 0.f;
      for (int i = 0; i < 256; ++i) {
        s0 += mid[i];
        s1 += mid[512 + i];
      }
      ws[WS_C0] = s0 + actor_b[0];
      ws[WS_C1] = s1;
    }
  }
}

__global__ __launch_bounds__(256) void head_kernel(
    const float* __restrict__ valid_mask, const float* __restrict__ log_std,
    const float* __restrict__ vu_w1, const float* __restrict__ vu_b1,
    const float* __restrict__ vu_w2, const float* __restrict__ vu_b2,
    const float* __restrict__ vc_w1, const float* __restrict__ vc_b1,
    const float* __restrict__ vc_w2, const float* __restrict__ vc_b2,
    const float* __restrict__ ws, float* __restrict__ out) {
  const int tid = threadIdx.x;
  const int blk = blockIdx.x;
  if (blk < 16) {
    // ---------------- value heads: block = (head, b) ----------------
    const int head = blk >> 3;
    const int b = blk & 7;
    __shared__ __align__(16) float vci[768];
    __shared__ float lm[256];
    __shared__ float red[8];
    lm[tid] = valid_mask[b * T_ + tid];
    __syncthreads();
    float m = wave_sum(lm[tid]);
    if ((tid & 63) == 0) red[tid >> 6] = m;
    __syncthreads();
    const float mdiv = 1.f / fmaxf(red[0] + red[1] + red[2] + red[3], 1.f);
    float acc = 0.f;
    const float* tf = ws + WS_TFEAT + b * T_ * D_;
    for (int t = 0; t < T_; ++t) acc = fmaf(tf[t * D_ + tid], lm[t], acc);
    vci[tid] = acc * mdiv;
    acc = 0.f;
    const float* wf = ws + WS_WFEAT + b * W_ * D_;
    for (int w = 0; w < W_; ++w) acc += wf[w * D_ + tid];
    vci[256 + tid] = acc * (1.f / 64.f);
    vci[512 + tid] = ws[WS_GFEAT + b * D_ + tid];
    __syncthreads();
    const float* w1 = head ? vc_w1 : vu_w1;
    const float* b1 = head ? vc_b1 : vu_b1;
    const float* w2 = head ? vc_w2 : vu_w2;
    const float* b2 = head ? vc_b2 : vu_b2;
    float h = 0.f;
    for (int k = 0; k < 768; k += 4) {
      float4 xv = *reinterpret_cast<const float4*>(&vci[k]);
      h = fmaf(xv.x, w1[(k + 0) * D_ + tid], h);
      h = fmaf(xv.y, w1[(k + 1) * D_ + tid], h);
      h = fmaf(xv.z, w1[(k + 2) * D_ + tid], h);
      h = fmaf(xv.w, w1[(k + 3) * D_ + tid], h);
    }
    h = fmaxf(h + b1[tid], 0.f);
    float c = h * w2[tid];
    c = wave_sum(c);
    __syncthreads();
    if ((tid & 63) == 0) red[tid >> 6] = c;
    __syncthreads();
    if (tid == 0)
      out[2 * B_ * W_ * T_ + head * B_ + b] =
          red[0] + red[1] + red[2] + red[3] + b2[0];
  } else {
    // ---------------- actor: mean + std, 2 elems/thread ----------------
    const int base = (blk - 16) * 512 + tid * 2;
    const float C0 = ws[WS_C0];
    const float C1 = ws[WS_C1];
#pragma unroll
    for (int e = 0; e < 2; ++e) {
      const int idx = base + e;
      const int b = idx >> 14;        // / (W*T)
      const int w = (idx >> 8) & 63;  // / T % W
      const int t = idx & 255;        // % T
      float S = ws[WS_SW + b * W_ + w] + ws[WS_ST + b * T_ + t] + ws[WS_SG + b];
      float sum =
          ws[WS_SUMW + b * W_ + w] + ws[WS_SUMT + b * T_ + t] + ws[WS_SUMG + b];
      float ssq =
          ws[WS_SSW + b * W_ + w] + ws[WS_SST + b * T_ + t] + ws[WS_SSG + b];
      float mu = sum * (1.f / 768.f);
      float var = ssq * (1.f / 768.f) - mu * mu;
      float inv = rsqrtf(var + 1e-5f);
      float logit = inv * (S - mu * C1) + C0;
      out[idx] = 1.f / (1.f + expf(-logit));
      float ls = log_std[w * T_ + t];
      out[B_ * W_ * T_ + idx] = expf(fminf(fmaxf(ls, -4.f), 1.f));
    }
  }
}

}  // namespace

extern "C" void kernel_launch(void* const* d_in, const int* in_sizes, int n_in,
                              void* d_out, int out_size, void* d_ws,
                              size_t ws_size, hipStream_t stream) {
  (void)in_sizes; (void)n_in; (void)out_size; (void)ws_size;
  const float* task_obs        = (const float*)d_in[0];
  const float* worker_loads    = (const float*)d_in[1];
  const float* worker_profiles = (const float*)d_in[2];
  const float* global_context  = (const float*)d_in[3];
  const float* valid_mask      = (const float*)d_in[4];
  const float* te_w1  = (const float*)d_in[5];
  const float* te_b1  = (const float*)d_in[6];
  const float* te_w2  = (const float*)d_in[7];
  const float* te_b2  = (const float*)d_in[8];
  const float* wle_w1 = (const float*)d_in[9];
  const float* wle_b1 = (const float*)d_in[10];
  const float* wle_w2 = (const float*)d_in[11];
  const float* wle_b2 = (const float*)d_in[12];
  const float* wpe_w1 = (const float*)d_in[13];
  const float* wpe_b1 = (const float*)d_in[14];
  const float* wpe_w2 = (const float*)d_in[15];
  const float* wpe_b2 = (const float*)d_in[16];
  const float* ft_w   = (const float*)d_in[17];
  const float* ft_b   = (const float*)d_in[18];
  const float* ft_g   = (const float*)d_in[19];
  const float* ft_bt  = (const float*)d_in[20];
  const float* fw_w   = (const float*)d_in[21];
  const float* fw_b   = (const float*)d_in[22];
  const float* fw_g   = (const float*)d_in[23];
  const float* fw_bt  = (const float*)d_in[24];
  const float* g_w1   = (const float*)d_in[25];
  const float* g_b1   = (const float*)d_in[26];
  const float* g_w2   = (const float*)d_in[27];
  const float* g_b2   = (const float*)d_in[28];
  const float* fn_g   = (const float*)d_in[29];
  const float* fn_b   = (const float*)d_in[30];
  const float* actor_w = (const float*)d_in[31];
  const float* actor_b = (const float*)d_in[32];
  const float* log_std = (const float*)d_in[33];
  const float* vu_w1  = (const float*)d_in[34];
  const float* vu_b1  = (const float*)d_in[35];
  const float* vu_w2  = (const float*)d_in[36];
  const float* vu_b2  = (const float*)d_in[37];
  const float* vc_w1  = (const float*)d_in[38];
  const float* vc_b1  = (const float*)d_in[39];
  const float* vc_w2  = (const float*)d_in[40];
  const float* vc_b2  = (const float*)d_in[41];
  float* ws = (float*)d_ws;
  float* out = (float*)d_out;

  hipLaunchKernelGGL(enc_kernel, dim3(385), dim3(256), 0, stream, task_obs,
                     worker_loads, worker_profiles, global_context, te_w1,
                     te_b1, te_w2, te_b2, wle_w1, wle_b1, wle_w2, wle_b2,
                     wpe_w1, wpe_b1, wpe_w2, wpe_b2, ft_w, ft_b, ft_g, ft_bt,
                     fw_w, fw_b, fw_g, fw_bt, g_w1, g_b1, g_w2, g_b2, fn_g,
                     fn_b, actor_w, actor_b, ws);
  hipLaunchKernelGGL(head_kernel, dim3(272), dim3(256), 0, stream, valid_mask,
                     log_std, vu_w1, vu_b1, vu_w2, vu_b2, vc_w1, vc_b1, vc_w2,
                     vc_b2, (const float*)ws, out);
}

// Round 3
// 50.620 us; speedup vs baseline: 1.1493x; 1.1493x over previous
//
#include <hip/hip_runtime.h>
#include <math.h>

namespace {

constexpr int B_ = 8, W_ = 64, T_ = 256, D_ = 256;
constexpr int TI_ = 32, WL_ = 16, WP_ = 24, G_ = 64;

typedef _Float16 h2 __attribute__((ext_vector_type(2)));
typedef __fp16 fp16v2 __attribute__((ext_vector_type(2)));

// -------- workspace layout (float offsets) --------
constexpr int WS_TFEAT = 0;                         // B*T*D
constexpr int WS_WFEAT = WS_TFEAT + B_ * T_ * D_;   // B*W*D
constexpr int WS_GFEAT = WS_WFEAT + B_ * W_ * D_;   // B*D
constexpr int WS_ST    = WS_GFEAT + B_ * D_;        // B*T
constexpr int WS_SUMT  = WS_ST + B_ * T_;
constexpr int WS_SST   = WS_SUMT + B_ * T_;
constexpr int WS_SW    = WS_SST + B_ * T_;          // B*W
constexpr int WS_SUMW  = WS_SW + B_ * W_;
constexpr int WS_SSW   = WS_SUMW + B_ * W_;
constexpr int WS_SG    = WS_SSW + B_ * W_;          // B
constexpr int WS_SUMG  = WS_SG + B_;
constexpr int WS_SSG   = WS_SUMG + B_;
constexpr int WS_C0    = WS_SSG + B_;
constexpr int WS_C1    = WS_C0 + 1;
constexpr int WS_PK    = 665120;  // 16B-aligned float offset; packed weights live here

// packed-weight offsets in uint4 units (each uint4 = 4 k-pairs = 8 k rows, 1 col)
constexpr int PK_TE1  = 0;       // 32x256   -> 1024
constexpr int PK_TE2  = 1024;    // 256x256  -> 8192
constexpr int PK_FT   = 9216;    // 256x256
constexpr int PK_WLE1 = 17408;   // 16x256   -> 512
constexpr int PK_WLE2 = 17920;   // 256x256
constexpr int PK_WPE1 = 26112;   // 24x256   -> 768
constexpr int PK_WPE2 = 26880;   // 256x256
constexpr int PK_FW   = 35072;   // 512x256  -> 16384
constexpr int PK_G1   = 51456;   // 64x256   -> 2048
constexpr int PK_G2   = 53504;   // 256x256
constexpr int PK_VU1  = 61696;   // 768x256  -> 24576
constexpr int PK_VC1  = 86272;   // 768x256
constexpr int PK_TOTAL = 110848; // uint4 count; grid = 110848/256 = 433 blocks

__device__ __forceinline__ float wave_sum(float v) {
#pragma unroll
  for (int m = 32; m > 0; m >>= 1) v += __shfl_xor(v, m, 64);
  return v;
}

__device__ __forceinline__ unsigned pkrtz_u(float a, float b) {
  fp16v2 p = __builtin_amdgcn_cvt_pkrtz(a, b);
  return __builtin_bit_cast(unsigned, p);
}

__device__ __forceinline__ float fdot2u(unsigned x, unsigned w, float c) {
#if __has_builtin(__builtin_amdgcn_fdot2)
  return __builtin_amdgcn_fdot2(__builtin_bit_cast(h2, x),
                                __builtin_bit_cast(h2, w), c, false);
#else
  h2 a = __builtin_bit_cast(h2, x);
  h2 b = __builtin_bit_cast(h2, w);
  float r = fmaf((float)a.x, (float)b.x, c);
  return fmaf((float)a.y, (float)b.y, r);
#endif
}

// R rows x 256 cols, K = 8*G. Wp: matrix base, layout [g][256 cols][uint4 of 4
// k-pairs]. xp: LDS packed activations, [r][xs uint4]. Thread owns col d.
template <int R, int G>
__device__ __forceinline__ void gemmp(const uint4* __restrict__ Wp,
                                      const uint4* xp, int xs, int d,
                                      float* acc) {
#pragma unroll
  for (int r = 0; r < R; ++r) acc[r] = 0.f;
#pragma unroll 4
  for (int g = 0; g < G; ++g) {
    uint4 w = Wp[g * 256 + d];
#pragma unroll
    for (int r = 0; r < R; ++r) {
      uint4 x = xp[r * xs + g];
      acc[r] = fdot2u(x.x, w.x, acc[r]);
      acc[r] = fdot2u(x.y, w.y, acc[r]);
      acc[r] = fdot2u(x.z, w.z, acc[r]);
      acc[r] = fdot2u(x.w, w.w, acc[r]);
    }
  }
}

// Pack fp32 column values (thread d owns col d) into f16-pair LDS rows via
// lane-pair shuffle. dst[r*stride + d/2] (u32 units). Caller barriers after.
template <int R>
__device__ __forceinline__ void shfl_pack(const float* v, unsigned* dst,
                                          int stride, int d) {
#pragma unroll
  for (int r = 0; r < R; ++r) {
    float p = __shfl_xor(v[r], 1, 64);
    unsigned pk = (d & 1) ? pkrtz_u(p, v[r]) : pkrtz_u(v[r], p);
    if (!(d & 1)) dst[r * stride + (d >> 1)] = pk;
  }
}

// LayerNorm R rows of h (LDS, stride 256) -> dst, plus fusion stats.
template <int R>
__device__ __forceinline__ void ln_stats(const float* h,
                                         const float* __restrict__ g,
                                         const float* __restrict__ bt,
                                         const float* __restrict__ fn_g_seg,
                                         const float* __restrict__ aw_seg,
                                         float* __restrict__ dst, int grow0,
                                         float* __restrict__ Sarr,
                                         float* __restrict__ sumarr,
                                         float* __restrict__ ssarr, int tid) {
  const int wv = tid >> 6, lane = tid & 63;
  for (int r = wv; r < R; r += 4) {
    float s = 0.f, ss = 0.f;
    for (int j = lane; j < D_; j += 64) {
      float v = h[r * D_ + j];
      s += v;
      ss = fmaf(v, v, ss);
    }
    s = wave_sum(s);
    ss = wave_sum(ss);
    float mu = s * (1.f / D_);
    float var = ss * (1.f / D_) - mu * mu;
    float inv = rsqrtf(var + 1e-5f);
    float a1 = 0.f, a2 = 0.f, a3 = 0.f;
    for (int j = lane; j < D_; j += 64) {
      float v = (h[r * D_ + j] - mu) * inv * g[j] + bt[j];
      dst[(grow0 + r) * D_ + j] = v;
      a1 = fmaf(v, fn_g_seg[j] * aw_seg[j], a1);
      a2 += v;
      a3 = fmaf(v, v, a3);
    }
    a1 = wave_sum(a1);
    a2 = wave_sum(a2);
    a3 = wave_sum(a3);
    if (lane == 0) {
      Sarr[grow0 + r] = a1;
      sumarr[grow0 + r] = a2;
      ssarr[grow0 + r] = a3;
    }
  }
}

// -------------------- weight pre-pack (fp32 -> f16 k-pairs) --------------------
__global__ __launch_bounds__(256) void pack_kernel(
    const float* __restrict__ te_w1, const float* __restrict__ te_w2,
    const float* __restrict__ ft_w, const float* __restrict__ wle_w1,
    const float* __restrict__ wle_w2, const float* __restrict__ wpe_w1,
    const float* __restrict__ wpe_w2, const float* __restrict__ fw_w,
    const float* __restrict__ g_w1, const float* __restrict__ g_w2,
    const float* __restrict__ vu_w1, const float* __restrict__ vc_w1,
    uint4* __restrict__ dst) {
  int i = blockIdx.x * 256 + threadIdx.x;
  const float* src;
  int off;
  if      (i < PK_TE2)  { src = te_w1;  off = PK_TE1;  }
  else if (i < PK_FT)   { src = te_w2;  off = PK_TE2;  }
  else if (i < PK_WLE1) { src = ft_w;   off = PK_FT;   }
  else if (i < PK_WLE2) { src = wle_w1; off = PK_WLE1; }
  else if (i < PK_WPE1) { src = wle_w2; off = PK_WLE2; }
  else if (i < PK_WPE2) { src = wpe_w1; off = PK_WPE1; }
  else if (i < PK_FW)   { src = wpe_w2; off = PK_WPE2; }
  else if (i < PK_G1)   { src = fw_w;   off = PK_FW;   }
  else if (i < PK_G2)   { src = g_w1;   off = PK_G1;   }
  else if (i < PK_VU1)  { src = g_w2;   off = PK_G2;   }
  else if (i < PK_VC1)  { src = vu_w1;  off = PK_VU1;  }
  else                  { src = vc_w1;  off = PK_VC1;  }
  int li = i - off;
  int g = li >> 8, d = li & 255;
  const float* p = src + (size_t)g * 8 * 256 + d;
  unsigned r[4];
#pragma unroll
  for (int j = 0; j < 4; ++j) {
    h2 pk;
    pk.x = (_Float16)p[(2 * j) * 256];      // RTN
    pk.y = (_Float16)p[(2 * j + 1) * 256];
    r[j] = __builtin_bit_cast(unsigned, pk);
  }
  uint4 o;
  o.x = r[0]; o.y = r[1]; o.z = r[2]; o.w = r[3];
  dst[i] = o;
}

// -------------------- fused encoders --------------------
// LDS packed-activation offsets (u32 units), all 16B aligned
constexpr int SP_X   = 0;     // task 64 / global 256
constexpr int SP_XL  = 0;     // worker loads 16
constexpr int SP_XP  = 16;    // worker profiles 24
constexpr int SP_MID = 256;   // up to 8x128
constexpr int SP_CAT = 1280;  // up to 2x256

__global__ __launch_bounds__(256) void enc_kernel(
    const float* __restrict__ task_obs, const float* __restrict__ worker_loads,
    const float* __restrict__ worker_profiles,
    const float* __restrict__ global_context, const float* __restrict__ te_b1,
    const float* __restrict__ te_b2, const float* __restrict__ wle_b1,
    const float* __restrict__ wle_b2, const float* __restrict__ wpe_b1,
    const float* __restrict__ wpe_b2, const float* __restrict__ ft_b,
    const float* __restrict__ ft_g, const float* __restrict__ ft_bt,
    const float* __restrict__ fw_b, const float* __restrict__ fw_g,
    const float* __restrict__ fw_bt, const float* __restrict__ g_b1,
    const float* __restrict__ g_b2, const float* __restrict__ fn_g,
    const float* __restrict__ fn_b, const float* __restrict__ actor_w,
    const float* __restrict__ actor_b, const uint4* __restrict__ wpk,
    float* __restrict__ ws) {
  __shared__ __align__(16) float smf[2064];
  __shared__ __align__(16) unsigned smp[1792];
  const int tid = threadIdx.x;
  const int d = tid;
  const int blk = blockIdx.x;

  if (blk < 512) {
    // ---------------- task path: 4 rows/block ----------------
    const int rb = blk * 4;
    if (tid < 64) {
      const float* src = task_obs + (size_t)rb * TI_;
      smp[SP_X + tid] = pkrtz_u(src[2 * tid], src[2 * tid + 1]);
    }
    __syncthreads();
    float acc[4], v[4];
    gemmp<4, 4>(wpk + PK_TE1, (const uint4*)(smp + SP_X), 4, d, acc);
    {
      float b = te_b1[d];
#pragma unroll
      for (int r = 0; r < 4; ++r) v[r] = fmaxf(acc[r] + b, 0.f);
      shfl_pack<4>(v, smp + SP_MID, 128, d);
    }
    __syncthreads();
    gemmp<4, 32>(wpk + PK_TE2, (const uint4*)(smp + SP_MID), 32, d, acc);
    {
      float b = te_b2[d];
#pragma unroll
      for (int r = 0; r < 4; ++r) v[r] = acc[r] + b;
      shfl_pack<4>(v, smp + SP_CAT, 128, d);
    }
    __syncthreads();
    gemmp<4, 32>(wpk + PK_FT, (const uint4*)(smp + SP_CAT), 32, d, acc);
    {
      float b = ft_b[d];
#pragma unroll
      for (int r = 0; r < 4; ++r) smf[r * D_ + d] = fmaxf(acc[r] + b, 0.f);
    }
    __syncthreads();
    ln_stats<4>(smf, ft_g, ft_bt, fn_g + 256, actor_w + 256, ws + WS_TFEAT, rb,
                ws + WS_ST, ws + WS_SUMT, ws + WS_SST, tid);
  } else if (blk < 768) {
    // ---------------- worker path: 2 rows/block ----------------
    const int rb = (blk - 512) * 2;
    if (tid < 16) {
      const float* src = worker_loads + (size_t)rb * WL_;
      smp[SP_XL + tid] = pkrtz_u(src[2 * tid], src[2 * tid + 1]);
    }
    if (tid < 24) {
      const float* src = worker_profiles + (size_t)rb * WP_;
      smp[SP_XP + tid] = pkrtz_u(src[2 * tid], src[2 * tid + 1]);
    }
    __syncthreads();
    float acc[2], v[2];
    gemmp<2, 2>(wpk + PK_WLE1, (const uint4*)(smp + SP_XL), 2, d, acc);
    {
      float b = wle_b1[d];
#pragma unroll
      for (int r = 0; r < 2; ++r) v[r] = fmaxf(acc[r] + b, 0.f);
      shfl_pack<2>(v, smp + SP_MID, 128, d);
    }
    __syncthreads();
    gemmp<2, 32>(wpk + PK_WLE2, (const uint4*)(smp + SP_MID), 32, d, acc);
    {
      float b = wle_b2[d];
#pragma unroll
      for (int r = 0; r < 2; ++r) v[r] = acc[r] + b;
      shfl_pack<2>(v, smp + SP_CAT, 256, d);
    }
    __syncthreads();
    gemmp<2, 3>(wpk + PK_WPE1, (const uint4*)(smp + SP_XP), 3, d, acc);
    {
      float b = wpe_b1[d];
#pragma unroll
      for (int r = 0; r < 2; ++r) v[r] = fmaxf(acc[r] + b, 0.f);
      shfl_pack<2>(v, smp + SP_MID, 128, d);
    }
    __syncthreads();
    gemmp<2, 32>(wpk + PK_WPE2, (const uint4*)(smp + SP_MID), 32, d, acc);
    {
      float b = wpe_b2[d];
#pragma unroll
      for (int r = 0; r < 2; ++r) v[r] = acc[r] + b;
      shfl_pack<2>(v, smp + SP_CAT + 128, 256, d);
    }
    __syncthreads();
    gemmp<2, 64>(wpk + PK_FW, (const uint4*)(smp + SP_CAT), 64, d, acc);
    {
      float b = fw_b[d];
#pragma unroll
      for (int r = 0; r < 2; ++r) smf[r * D_ + d] = fmaxf(acc[r] + b, 0.f);
    }
    __syncthreads();
    ln_stats<2>(smf, fw_g, fw_bt, fn_g, actor_w, ws + WS_WFEAT, rb, ws + WS_SW,
                ws + WS_SUMW, ws + WS_SSW, tid);
  } else {
    // ---------------- global path: 8 rows (one block) ----------------
    {
      smp[SP_X + tid] = pkrtz_u(global_context[2 * tid],
                                global_context[2 * tid + 1]);
    }
    __syncthreads();
    float acc[8], v[8];
    gemmp<8, 8>(wpk + PK_G1, (const uint4*)(smp + SP_X), 8, d, acc);
    {
      float b = g_b1[d];
#pragma unroll
      for (int r = 0; r < 8; ++r) v[r] = fmaxf(acc[r] + b, 0.f);
      shfl_pack<8>(v, smp + SP_MID, 128, d);
    }
    __syncthreads();
    gemmp<8, 32>(wpk + PK_G2, (const uint4*)(smp + SP_MID), 32, d, acc);
    {
      float b = g_b2[d];
#pragma unroll
      for (int r = 0; r < 8; ++r) {
        float x = acc[r] + b;
        ws[WS_GFEAT + r * D_ + d] = x;
        smf[r * D_ + d] = x;
      }
    }
    // C0/C1 partials
    float c0 = 0.f, c1 = 0.f;
    for (int i = tid; i < 768; i += 256) {
      float aw = actor_w[i];
      c0 = fmaf(fn_b[i], aw, c0);
      c1 = fmaf(fn_g[i], aw, c1);
    }
    c0 = wave_sum(c0);
    c1 = wave_sum(c1);
    const int wv = tid >> 6, lane = tid & 63;
    if (lane == 0) {
      smf[2048 + wv] = c0;
      smf[2052 + wv] = c1;
    }
    __syncthreads();
    for (int r = wv; r < 8; r += 4) {
      float a1 = 0.f, a2 = 0.f, a3 = 0.f;
      for (int j = lane; j < D_; j += 64) {
        float x = smf[r * D_ + j];
        a1 = fmaf(x, fn_g[512 + j] * actor_w[512 + j], a1);
        a2 += x;
        a3 = fmaf(x, x, a3);
      }
      a1 = wave_sum(a1);
      a2 = wave_sum(a2);
      a3 = wave_sum(a3);
      if (lane == 0) {
        ws[WS_SG + r] = a1;
        ws[WS_SUMG + r] = a2;
        ws[WS_SSG + r] = a3;
      }
    }
    if (tid == 0) {
      ws[WS_C0] = smf[2048] + smf[2049] + smf[2050] + smf[2051] + actor_b[0];
      ws[WS_C1] = smf[2052] + smf[2053] + smf[2054] + smf[2055];
    }
  }
}

// -------------------- heads --------------------
__global__ __launch_bounds__(256) void head_kernel(
    const float* __restrict__ valid_mask, const float* __restrict__ log_std,
    const float* __restrict__ vu_b1, const float* __restrict__ vu_b2,
    const float* __restrict__ vc_b1, const float* __restrict__ vc_b2,
    const float* __restrict__ vu_w2, const float* __restrict__ vc_w2,
    const uint4* __restrict__ wpk, const float* __restrict__ ws,
    float* __restrict__ out) {
  const int tid = threadIdx.x;
  const int blk = blockIdx.x;
  if (blk < 16) {
    // ---------------- value heads: block = (head, b) ----------------
    const int head = blk >> 3;
    const int b = blk & 7;
    __shared__ float lm[256];
    __shared__ float red[8];
    __shared__ __align__(16) unsigned vcip[384];
    lm[tid] = valid_mask[b * T_ + tid];
    __syncthreads();
    float m = wave_sum(lm[tid]);
    if ((tid & 63) == 0) red[tid >> 6] = m;
    __syncthreads();
    const float mdiv = 1.f / fmaxf(red[0] + red[1] + red[2] + red[3], 1.f);
    float vv[3];
    {
      float acc = 0.f;
      const float* tf = ws + WS_TFEAT + b * T_ * D_;
      for (int t = 0; t < T_; ++t) acc = fmaf(tf[t * D_ + tid], lm[t], acc);
      vv[0] = acc * mdiv;
      acc = 0.f;
      const float* wf = ws + WS_WFEAT + b * W_ * D_;
      for (int w = 0; w < W_; ++w) acc += wf[w * D_ + tid];
      vv[1] = acc * (1.f / 64.f);
      vv[2] = ws[WS_GFEAT + b * D_ + tid];
    }
    shfl_pack<3>(vv, vcip, 128, tid);
    __syncthreads();
    const uint4* w1p = wpk + (head ? PK_VC1 : PK_VU1);
    const float* b1 = head ? vc_b1 : vu_b1;
    const float* w2 = head ? vc_w2 : vu_w2;
    const float* b2 = head ? vc_b2 : vu_b2;
    float h = 0.f;
    const uint4* xq = (const uint4*)vcip;
#pragma unroll 4
    for (int g = 0; g < 96; ++g) {
      uint4 w = w1p[g * 256 + tid];
      uint4 x = xq[g];
      h = fdot2u(x.x, w.x, h);
      h = fdot2u(x.y, w.y, h);
      h = fdot2u(x.z, w.z, h);
      h = fdot2u(x.w, w.w, h);
    }
    h = fmaxf(h + b1[tid], 0.f);
    float c = wave_sum(h * w2[tid]);
    __syncthreads();
    if ((tid & 63) == 0) red[tid >> 6] = c;
    __syncthreads();
    if (tid == 0)
      out[2 * B_ * W_ * T_ + head * B_ + b] =
          red[0] + red[1] + red[2] + red[3] + b2[0];
  } else {
    // ---------------- actor: mean + std, 2 elems/thread ----------------
    const int base = (blk - 16) * 512 + tid * 2;
    const float C0 = ws[WS_C0];
    const float C1 = ws[WS_C1];
#pragma unroll
    for (int e = 0; e < 2; ++e) {
      const int idx = base + e;
      const int b = idx >> 14;
      const int w = (idx >> 8) & 63;
      const int t = idx & 255;
      float S = ws[WS_SW + b * W_ + w] + ws[WS_ST + b * T_ + t] + ws[WS_SG + b];
      float sum =
          ws[WS_SUMW + b * W_ + w] + ws[WS_SUMT + b * T_ + t] + ws[WS_SUMG + b];
      float ssq =
          ws[WS_SSW + b * W_ + w] + ws[WS_SST + b * T_ + t] + ws[WS_SSG + b];
      float mu = sum * (1.f / 768.f);
      float var = ssq * (1.f / 768.f) - mu * mu;
      float inv = rsqrtf(var + 1e-5f);
      float logit = inv * (S - mu * C1) + C0;
      out[idx] = 1.f / (1.f + expf(-logit));
      float ls = log_std[w * T_ + t];
      out[B_ * W_ * T_ + idx] = expf(fminf(fmaxf(ls, -4.f), 1.f));
    }
  }
}

}  // namespace

extern "C" void kernel_launch(void* const* d_in, const int* in_sizes, int n_in,
                              void* d_out, int out_size, void* d_ws,
                              size_t ws_size, hipStream_t stream) {
  (void)in_sizes; (void)n_in; (void)out_size; (void)ws_size;
  const float* task_obs        = (const float*)d_in[0];
  const float* worker_loads    = (const float*)d_in[1];
  const float* worker_profiles = (const float*)d_in[2];
  const float* global_context  = (const float*)d_in[3];
  const float* valid_mask      = (const float*)d_in[4];
  const float* te_w1  = (const float*)d_in[5];
  const float* te_b1  = (const float*)d_in[6];
  const float* te_w2  = (const float*)d_in[7];
  const float* te_b2  = (const float*)d_in[8];
  const float* wle_w1 = (const float*)d_in[9];
  const float* wle_b1 = (const float*)d_in[10];
  const float* wle_w2 = (const float*)d_in[11];
  const float* wle_b2 = (const float*)d_in[12];
  const float* wpe_w1 = (const float*)d_in[13];
  const float* wpe_b1 = (const float*)d_in[14];
  const float* wpe_w2 = (const float*)d_in[15];
  const float* wpe_b2 = (const float*)d_in[16];
  const float* ft_w   = (const float*)d_in[17];
  const float* ft_b   = (const float*)d_in[18];
  const float* ft_g   = (const float*)d_in[19];
  const float* ft_bt  = (const float*)d_in[20];
  const float* fw_w   = (const float*)d_in[21];
  const float* fw_b   = (const float*)d_in[22];
  const float* fw_g   = (const float*)d_in[23];
  const float* fw_bt  = (const float*)d_in[24];
  const float* g_w1   = (const float*)d_in[25];
  const float* g_b1   = (const float*)d_in[26];
  const float* g_w2   = (const float*)d_in[27];
  const float* g_b2   = (const float*)d_in[28];
  const float* fn_g   = (const float*)d_in[29];
  const float* fn_b   = (const float*)d_in[30];
  const float* actor_w = (const float*)d_in[31];
  const float* actor_b = (const float*)d_in[32];
  const float* log_std = (const float*)d_in[33];
  const float* vu_w1  = (const float*)d_in[34];
  const float* vu_b1  = (const float*)d_in[35];
  const float* vu_w2  = (const float*)d_in[36];
  const float* vu_b2  = (const float*)d_in[37];
  const float* vc_w1  = (const float*)d_in[38];
  const float* vc_b1  = (const float*)d_in[39];
  const float* vc_w2  = (const float*)d_in[40];
  const float* vc_b2  = (const float*)d_in[41];
  float* ws = (float*)d_ws;
  uint4* wpk = (uint4*)(ws + WS_PK);
  float* out = (float*)d_out;

  hipLaunchKernelGGL(pack_kernel, dim3(PK_TOTAL / 256), dim3(256), 0, stream,
                     te_w1, te_w2, ft_w, wle_w1, wle_w2, wpe_w1, wpe_w2, fw_w,
                     g_w1, g_w2, vu_w1, vc_w1, wpk);
  hipLaunchKernelGGL(enc_kernel, dim3(769), dim3(256), 0, stream, task_obs,
                     worker_loads, worker_profiles, global_context, te_b1,
                     te_b2, wle_b1, wle_b2, wpe_b1, wpe_b2, ft_b, ft_g, ft_bt,
                     fw_b, fw_g, fw_bt, g_b1, g_b2, fn_g, fn_b, actor_w,
                     actor_b, (const uint4*)wpk, ws);
  hipLaunchKernelGGL(head_kernel, dim3(272), dim3(256), 0, stream, valid_mask,
                     log_std, vu_b1, vu_b2, vc_b1, vc_b2, vu_w2, vc_w2,
                     (const uint4*)wpk, (const float*)ws, out);
}